// Round 21
// baseline (56.005 us; speedup 1.0000x reference)
//
#include <hip/hip_runtime.h>

#define S 512
#define Dm 512

typedef __bf16 bf16x8 __attribute__((ext_vector_type(8)));
typedef float f32x4 __attribute__((ext_vector_type(4)));

// ---------------- bf16 MFMA GEMM with in-kernel W staging (no prep dispatch) ----------------
// 32x32 tile, 256 thr = 2x2 waves of one 16x16 MFMA each.
// A: fp32 (inline cvt, contiguous) or bf16. W: fp32 [K][N], staged per BK=64 chunk
// into LDS as transposed bf16 Tl[n][kk] via coalesced float4 reads.
// TRANSQK: matrices m<2 written transposed (O^T[col][row]) for the z-pass.
template<bool A_BF16, bool TRANSQK>
__global__ __launch_bounds__(256) void gemm_stage(
    const void* __restrict__ Aptr,
    const float* __restrict__ W0, const float* __restrict__ W1, const float* __restrict__ W2,
    const float* __restrict__ b0, const float* __restrict__ b1, const float* __restrict__ b2,
    float* __restrict__ O0, float* __restrict__ O1, float* __restrict__ O2)
{
    int blk = blockIdx.x;
    int m = blk >> 8;
    int tile = blk & 255;
    const float* W = (m == 0) ? W0 : (m == 1) ? W1 : W2;
    const float* bias = (m == 0) ? b0 : (m == 1) ? b1 : b2;
    float* O = (m == 0) ? O0 : (m == 1) ? O1 : O2;
    int rt = tile >> 4, ct = tile & 15;

    int u = threadIdx.x;
    int w = u >> 6, lane = u & 63;
    int r = lane & 15, kg = lane >> 4;

    int row0 = (rt << 5) + ((w >> 1) << 4);
    int colb = ct << 5;                    // block column base
    int col0 = colb + ((w & 1) << 4);      // wave column base

    __shared__ __bf16 Tl[32][72];          // [n within tile][kk within chunk], pad 72

    f32x4 acc = {0.f, 0.f, 0.f, 0.f};

    int skk = u >> 2;                      // 0..63 staging row (k)
    int sn4 = (u & 3) << 3;                // 0,8,16,24 staging col group

    for (int k0 = 0; k0 < Dm; k0 += 64) {
        // ---- stage W chunk: W[k0+kk][colb+n] -> Tl[n][kk] (bf16) ----
        {
            const float* wp = W + (k0 + skk) * Dm + colb + sn4;
            float4 w0v = *(const float4*)(wp);
            float4 w1v = *(const float4*)(wp + 4);
            Tl[sn4 + 0][skk] = (__bf16)w0v.x;
            Tl[sn4 + 1][skk] = (__bf16)w0v.y;
            Tl[sn4 + 2][skk] = (__bf16)w0v.z;
            Tl[sn4 + 3][skk] = (__bf16)w0v.w;
            Tl[sn4 + 4][skk] = (__bf16)w1v.x;
            Tl[sn4 + 5][skk] = (__bf16)w1v.y;
            Tl[sn4 + 6][skk] = (__bf16)w1v.z;
            Tl[sn4 + 7][skk] = (__bf16)w1v.w;
        }
        __syncthreads();

        // ---- 2 MFMA k-steps on the staged chunk ----
        #pragma unroll
        for (int s = 0; s < 2; ++s) {
            int ks = k0 + (s << 5);
            bf16x8 a;
            if constexpr (A_BF16) {
                const __bf16* Ab = (const __bf16*)Aptr;
                a = *(const bf16x8*)(Ab + (row0 + r) * Dm + ks + (kg << 3));
            } else {
                const float* Af = (const float*)Aptr;
                float4 a0 = *(const float4*)(Af + (row0 + r) * Dm + ks + (kg << 3));
                float4 a1 = *(const float4*)(Af + (row0 + r) * Dm + ks + (kg << 3) + 4);
                a[0] = (__bf16)a0.x; a[1] = (__bf16)a0.y; a[2] = (__bf16)a0.z; a[3] = (__bf16)a0.w;
                a[4] = (__bf16)a1.x; a[5] = (__bf16)a1.y; a[6] = (__bf16)a1.z; a[7] = (__bf16)a1.w;
            }
            bf16x8 b = *(const bf16x8*)&Tl[((w & 1) << 4) + r][(s << 5) + (kg << 3)];
            acc = __builtin_amdgcn_mfma_f32_16x16x32_bf16(a, b, acc, 0, 0, 0);
        }
        __syncthreads();
    }

    int orow = row0 + (kg << 2);
    float bb = bias[col0 + r];

    if constexpr (TRANSQK) {
        if (m < 2) {
            float4 o = make_float4(acc[0] + bb, acc[1] + bb, acc[2] + bb, acc[3] + bb);
            *(float4*)(O + (col0 + r) * S + orow) = o;
            return;
        }
    }
    #pragma unroll
    for (int t = 0; t < 4; ++t)
        O[(orow + t) * Dm + col0 + r] = acc[t] + bb;
}

// ---------------- fused z' + ctx (r20, unchanged) ----------------
__global__ __launch_bounds__(512) void zctx_kernel(
    const float* __restrict__ QT, const float* __restrict__ KT, const float* __restrict__ V,
    const float* __restrict__ mask, const float* __restrict__ gamma,
    const float* __restrict__ alpha, __bf16* __restrict__ ctxb)
{
    int blk = blockIdx.x;
    int h  = blk >> 6;
    int it = blk & 63;
    int i0 = it << 3;
    int c0 = h << 6;

    int u = threadIdx.x;
    int w = u >> 6, lane = u & 63;
    int jj = (w << 6) + lane;

    __shared__ float zs[8][512];
    __shared__ float zpart[8][8];
    __shared__ float part[8][8][64];

    const float* kcol = KT + (c0 * S) + jj;
    const float* qrow = QT + (c0 * S) + i0;

    float acc[8] = {};
    #pragma unroll 4
    for (int d = 0; d < 64; ++d) {
        float kv = kcol[d * S];
        float4 qa = *(const float4*)(qrow + d * S);
        float4 qb = *(const float4*)(qrow + d * S + 4);
        acc[0] += fabsf(qa.x - kv);
        acc[1] += fabsf(qa.y - kv);
        acc[2] += fabsf(qa.z - kv);
        acc[3] += fabsf(qa.w - kv);
        acc[4] += fabsf(qb.x - kv);
        acc[5] += fabsf(qb.y - kv);
        acc[6] += fabsf(qb.z - kv);
        acc[7] += fabsf(qb.w - kv);
    }

    float sc = 1.0f / (gamma[0] * 8.0f);
    float al = alpha[0];
    float madd = (1.0f - mask[jj]) * 1e6f;

    float zpv[8];
    #pragma unroll
    for (int r = 0; r < 8; ++r) {
        zpv[r] = fmaxf(acc[r] * sc - al, 0.0f) + madd;
        zs[r][jj] = zpv[r];
    }

    #pragma unroll
    for (int r = 0; r < 8; ++r) {
        float v = zpv[r];
        v += __shfl_xor(v, 1, 64);
        v += __shfl_xor(v, 2, 64);
        v += __shfl_xor(v, 4, 64);
        v += __shfl_xor(v, 8, 64);
        v += __shfl_xor(v, 16, 64);
        v += __shfl_xor(v, 32, 64);
        zpv[r] = v;
    }
    if (lane == 0) {
        #pragma unroll
        for (int r = 0; r < 8; ++r) zpart[w][r] = zpv[r];
    }
    __syncthreads();

    int wu = __builtin_amdgcn_readfirstlane(w);
    float a2[8][4] = {};

    #pragma unroll
    for (int cch = 0; cch < 4; ++cch) {
        int jg = (cch << 7) + (wu << 4);
        float vv[16];
        #pragma unroll
        for (int t = 0; t < 16; ++t)
            vv[t] = V[(jg + t) * Dm + c0 + lane];

        #pragma unroll
        for (int ii = 0; ii < 8; ++ii) {
            #pragma unroll
            for (int q4 = 0; q4 < 4; ++q4) {
                float4 z4 = *(const float4*)&zs[ii][jg + (q4 << 2)];
                a2[ii][0] += fmaxf(vv[(q4 << 2) + 0], z4.x);
                a2[ii][1] += fmaxf(vv[(q4 << 2) + 1], z4.y);
                a2[ii][2] += fmaxf(vv[(q4 << 2) + 2], z4.z);
                a2[ii][3] += fmaxf(vv[(q4 << 2) + 3], z4.w);
            }
        }
    }

    #pragma unroll
    for (int ii = 0; ii < 8; ++ii)
        part[w][ii][lane] = (a2[ii][0] + a2[ii][1]) + (a2[ii][2] + a2[ii][3]);
    __syncthreads();

    {
        int ii = u >> 6;
        float s = 0.f;
        #pragma unroll
        for (int ww = 0; ww < 8; ++ww) s += part[ww][ii][lane];
        float zsum = 0.f;
        #pragma unroll
        for (int p = 0; p < 8; ++p) zsum += zpart[p][ii];
        ctxb[(i0 + ii) * Dm + c0 + lane] = (__bf16)(s - zsum);
    }
}

extern "C" void kernel_launch(void* const* d_in, const int* in_sizes, int n_in,
                              void* d_out, int out_size, void* d_ws, size_t ws_size,
                              hipStream_t stream) {
    const float* hs    = (const float*)d_in[0];
    const float* mask  = (const float*)d_in[1];
    const float* Wq    = (const float*)d_in[2];
    const float* bq    = (const float*)d_in[3];
    const float* Wk    = (const float*)d_in[4];
    const float* bk    = (const float*)d_in[5];
    const float* Wv    = (const float*)d_in[6];
    const float* bv    = (const float*)d_in[7];
    const float* Wo    = (const float*)d_in[8];
    const float* bo    = (const float*)d_in[9];
    const float* gamma = (const float*)d_in[10];
    const float* alpha = (const float*)d_in[11];
    float* out = (float*)d_out;

    char* base = (char*)d_ws;
    float*  QT  = (float*)(base);                      // 1 MB (transposed)
    float*  KT  = QT + S * Dm;                         // 1 MB (transposed)
    float*  Vb  = KT + S * Dm;                         // 1 MB
    __bf16* Cbf = (__bf16*)(Vb + S * Dm);              // 0.5 MB

    hipLaunchKernelGGL((gemm_stage<false, true>), dim3(768), dim3(256), 0, stream,
                       (const void*)hs, Wq, Wk, Wv, bq, bk, bv, QT, KT, Vb);
    hipLaunchKernelGGL(zctx_kernel, dim3(512), dim3(512), 0, stream,
                       QT, KT, Vb, mask, gamma, alpha, Cbf);
    hipLaunchKernelGGL((gemm_stage<true, false>), dim3(256), dim3(256), 0, stream,
                       (const void*)Cbf, Wo, Wo, Wo, bo, bo, bo, out, out, out);
}

// Round 22
// 55.787 us; speedup vs baseline: 1.0039x; 1.0039x over previous
//
#include <hip/hip_runtime.h>

#define S 512
#define Dm 512

typedef __bf16 bf16x8 __attribute__((ext_vector_type(8)));
typedef float f32x4 __attribute__((ext_vector_type(4)));

__device__ __forceinline__ float bflo(unsigned int u) { return __uint_as_float(u << 16); }
__device__ __forceinline__ float bfhi(unsigned int u) { return __uint_as_float(u & 0xffff0000u); }

// ---------------- prep: hs->bf16 (blocks 0..127) ; W->WT bf16 (blocks 128..383) ----------------
__global__ __launch_bounds__(256) void prep_kernel(
    const float* __restrict__ hs,
    const float* __restrict__ W0, const float* __restrict__ W1,
    const float* __restrict__ W2, const float* __restrict__ W3,
    __bf16* __restrict__ Abf,
    __bf16* __restrict__ T0, __bf16* __restrict__ T1,
    __bf16* __restrict__ T2, __bf16* __restrict__ T3)
{
    __shared__ __bf16 Tl[64][72];
    int u = threadIdx.x;
    if (blockIdx.x < 128) {
        int i = (blockIdx.x * 256 + u) * 8;
        float4 x0 = *(const float4*)(hs + i);
        float4 x1 = *(const float4*)(hs + i + 4);
        bf16x8 y;
        y[0] = (__bf16)x0.x; y[1] = (__bf16)x0.y; y[2] = (__bf16)x0.z; y[3] = (__bf16)x0.w;
        y[4] = (__bf16)x1.x; y[5] = (__bf16)x1.y; y[6] = (__bf16)x1.z; y[7] = (__bf16)x1.w;
        *(bf16x8*)(Abf + i) = y;
        return;
    }
    int blk = blockIdx.x - 128;
    int m = blk >> 6;
    int t = blk & 63;
    const float* W = (m == 0) ? W0 : (m == 1) ? W1 : (m == 2) ? W2 : W3;
    __bf16* T = (m == 0) ? T0 : (m == 1) ? T1 : (m == 2) ? T2 : T3;
    int k0 = (t >> 3) << 6;
    int n0 = (t & 7) << 6;
    {
        int kk = u >> 4;
        int n4 = (u & 15) << 2;
        #pragma unroll
        for (int p = 0; p < 4; ++p) {
            int k = kk + (p << 4);
            float4 wv = *(const float4*)(W + (k0 + k) * Dm + n0 + n4);
            Tl[n4 + 0][k] = (__bf16)wv.x;
            Tl[n4 + 1][k] = (__bf16)wv.y;
            Tl[n4 + 2][k] = (__bf16)wv.z;
            Tl[n4 + 3][k] = (__bf16)wv.w;
        }
    }
    __syncthreads();
    {
        int n = u >> 2;
        int ks = (u & 3) << 4;
        uint4 d0 = *(const uint4*)&Tl[n][ks];
        uint4 d1 = *(const uint4*)&Tl[n][ks + 8];
        *(uint4*)(T + (n0 + n) * Dm + k0 + ks) = d0;
        *(uint4*)(T + (n0 + n) * Dm + k0 + ks + 8) = d1;
    }
}

// ---------------- bf16 MFMA GEMM, contiguous bf16 fragments (r20) ----------------
template<bool TRANSQK>
__global__ __launch_bounds__(256) void gemm_bf(
    const __bf16* __restrict__ Abf,
    const __bf16* __restrict__ T0, const __bf16* __restrict__ T1, const __bf16* __restrict__ T2,
    const float* __restrict__ b0, const float* __restrict__ b1, const float* __restrict__ b2,
    float* __restrict__ O0, float* __restrict__ O1, float* __restrict__ O2)
{
    int blk = blockIdx.x;
    int m = blk >> 8;
    int tile = blk & 255;
    const __bf16* T = (m == 0) ? T0 : (m == 1) ? T1 : T2;
    const float* bias = (m == 0) ? b0 : (m == 1) ? b1 : b2;
    float* O = (m == 0) ? O0 : (m == 1) ? O1 : O2;
    int rt = tile >> 4, ct = tile & 15;

    int u = threadIdx.x;
    int w = u >> 6, lane = u & 63;
    int r = lane & 15, kg = lane >> 4;

    int row0 = (rt << 5) + ((w >> 1) << 4);
    int col0 = (ct << 5) + ((w & 1) << 4);

    const __bf16* Ap = Abf + (row0 + r) * Dm + (kg << 3);
    const __bf16* Bp = T + (col0 + r) * Dm + (kg << 3);

    f32x4 acc = {0.f, 0.f, 0.f, 0.f};

    #pragma unroll 4
    for (int k0 = 0; k0 < Dm; k0 += 32) {
        bf16x8 a = *(const bf16x8*)(Ap + k0);
        bf16x8 b = *(const bf16x8*)(Bp + k0);
        acc = __builtin_amdgcn_mfma_f32_16x16x32_bf16(a, b, acc, 0, 0, 0);
    }

    int orow = row0 + (kg << 2);
    float bb = bias[col0 + r];

    if constexpr (TRANSQK) {
        if (m < 2) {
            float4 o = make_float4(acc[0] + bb, acc[1] + bb, acc[2] + bb, acc[3] + bb);
            *(float4*)(O + (col0 + r) * S + orow) = o;
            return;
        }
    }
    #pragma unroll
    for (int t = 0; t < 4; ++t)
        O[(orow + t) * Dm + col0 + r] = acc[t] + bb;
}

// ---------------- fused z' + ctx, bf16 z'-tile in [j][ii] layout ----------------
// grid 512 = 8 heads * 64 i-tiles(8 rows). 512 thr = 8 waves.
// Phase A: thread j = w*64+lane; KT col coalesced, QT rows scalar; z' rounded to bf16,
//   one ds_write_b128 per thread (8 rows contiguous); Zsum over ROUNDED values.
// Phase B: per (cch,t): one b128 broadcast read = all 8 rows for j -> 8 max+add.
//   DS instrs per wave halved vs fp32 [ii][j] layout (was 3x oversubscribed).
__global__ __launch_bounds__(512) void zctx_kernel(
    const float* __restrict__ QT, const float* __restrict__ KT, const float* __restrict__ V,
    const float* __restrict__ mask, const float* __restrict__ gamma,
    const float* __restrict__ alpha, __bf16* __restrict__ ctxb)
{
    int blk = blockIdx.x;
    int h  = blk >> 6;
    int it = blk & 63;
    int i0 = it << 3;
    int c0 = h << 6;

    int u = threadIdx.x;
    int w = u >> 6, lane = u & 63;
    int jj = (w << 6) + lane;

    __shared__ __bf16 zsb[512][8];     // 8 KB, [j][ii]
    __shared__ float zpart[8][8];
    __shared__ float part[8][8][64];   // 16 KB

    // ---- phase A: z' ----
    const float* kcol = KT + (c0 * S) + jj;
    const float* qrow = QT + (c0 * S) + i0;

    float acc[8] = {};
    #pragma unroll 4
    for (int d = 0; d < 64; ++d) {
        float kv = kcol[d * S];
        float4 qa = *(const float4*)(qrow + d * S);
        float4 qb = *(const float4*)(qrow + d * S + 4);
        acc[0] += fabsf(qa.x - kv);
        acc[1] += fabsf(qa.y - kv);
        acc[2] += fabsf(qa.z - kv);
        acc[3] += fabsf(qa.w - kv);
        acc[4] += fabsf(qb.x - kv);
        acc[5] += fabsf(qb.y - kv);
        acc[6] += fabsf(qb.z - kv);
        acc[7] += fabsf(qb.w - kv);
    }

    float sc = 1.0f / (gamma[0] * 8.0f);
    float al = alpha[0];
    float madd = (1.0f - mask[jj]) * 1e6f;

    bf16x8 zr8;
    float zrs[8];
    #pragma unroll
    for (int r = 0; r < 8; ++r) {
        float zpv = fmaxf(acc[r] * sc - al, 0.0f) + madd;
        __bf16 zb = (__bf16)zpv;
        zr8[r] = zb;
        zrs[r] = (float)zb;            // rounded value -> Zsum cancels exactly
    }
    *(bf16x8*)&zsb[jj][0] = zr8;       // one ds_write_b128

    #pragma unroll
    for (int r = 0; r < 8; ++r) {
        float v = zrs[r];
        v += __shfl_xor(v, 1, 64);
        v += __shfl_xor(v, 2, 64);
        v += __shfl_xor(v, 4, 64);
        v += __shfl_xor(v, 8, 64);
        v += __shfl_xor(v, 16, 64);
        v += __shfl_xor(v, 32, 64);
        zrs[r] = v;
    }
    if (lane == 0) {
        #pragma unroll
        for (int r = 0; r < 8; ++r) zpart[w][r] = zrs[r];
    }
    __syncthreads();

    // ---- phase B: ctx ----
    int wu = __builtin_amdgcn_readfirstlane(w);
    float a2[8] = {};

    #pragma unroll
    for (int cch = 0; cch < 4; ++cch) {
        int jg = (cch << 7) + (wu << 4);
        float vv[16];
        #pragma unroll
        for (int t = 0; t < 16; ++t)
            vv[t] = V[(jg + t) * Dm + c0 + lane];          // per-lane coalesced

        #pragma unroll
        for (int t = 0; t < 16; ++t) {
            uint4 zu = *(const uint4*)&zsb[jg + t][0];     // broadcast b128: 8 rows
            float vt = vv[t];
            a2[0] += fmaxf(vt, bflo(zu.x));
            a2[1] += fmaxf(vt, bfhi(zu.x));
            a2[2] += fmaxf(vt, bflo(zu.y));
            a2[3] += fmaxf(vt, bfhi(zu.y));
            a2[4] += fmaxf(vt, bflo(zu.z));
            a2[5] += fmaxf(vt, bfhi(zu.z));
            a2[6] += fmaxf(vt, bflo(zu.w));
            a2[7] += fmaxf(vt, bfhi(zu.w));
        }
    }

    #pragma unroll
    for (int ii = 0; ii < 8; ++ii)
        part[w][ii][lane] = a2[ii];
    __syncthreads();

    {
        int ii = u >> 6;
        float s = 0.f;
        #pragma unroll
        for (int ww = 0; ww < 8; ++ww) s += part[ww][ii][lane];
        float zsum = 0.f;
        #pragma unroll
        for (int p = 0; p < 8; ++p) zsum += zpart[p][ii];
        ctxb[(i0 + ii) * Dm + c0 + lane] = (__bf16)(s - zsum);
    }
}

extern "C" void kernel_launch(void* const* d_in, const int* in_sizes, int n_in,
                              void* d_out, int out_size, void* d_ws, size_t ws_size,
                              hipStream_t stream) {
    const float* hs    = (const float*)d_in[0];
    const float* mask  = (const float*)d_in[1];
    const float* Wq    = (const float*)d_in[2];
    const float* bq    = (const float*)d_in[3];
    const float* Wk    = (const float*)d_in[4];
    const float* bk    = (const float*)d_in[5];
    const float* Wv    = (const float*)d_in[6];
    const float* bv    = (const float*)d_in[7];
    const float* Wo    = (const float*)d_in[8];
    const float* bo    = (const float*)d_in[9];
    const float* gamma = (const float*)d_in[10];
    const float* alpha = (const float*)d_in[11];
    float* out = (float*)d_out;

    char* base = (char*)d_ws;
    float*  QT  = (float*)(base);                      // 1 MB (transposed)
    float*  KT  = QT + S * Dm;                         // 1 MB (transposed)
    float*  Vb  = KT + S * Dm;                         // 1 MB
    __bf16* Abf = (__bf16*)(Vb + S * Dm);              // 0.5 MB
    __bf16* T0  = Abf + S * Dm;                        // 0.5 MB each
    __bf16* T1  = T0 + S * Dm;
    __bf16* T2  = T1 + S * Dm;
    __bf16* T3  = T2 + S * Dm;
    __bf16* Cbf = T3 + S * Dm;                         // 0.5 MB

    hipLaunchKernelGGL(prep_kernel, dim3(384), dim3(256), 0, stream,
                       hs, Wq, Wk, Wv, Wo, Abf, T0, T1, T2, T3);
    hipLaunchKernelGGL((gemm_bf<true>), dim3(768), dim3(256), 0, stream,
                       Abf, T0, T1, T2, bq, bk, bv, QT, KT, Vb);
    hipLaunchKernelGGL(zctx_kernel, dim3(512), dim3(512), 0, stream,
                       QT, KT, Vb, mask, gamma, alpha, Cbf);
    hipLaunchKernelGGL((gemm_bf<false>), dim3(256), dim3(256), 0, stream,
                       Cbf, T3, T3, T3, bo, bo, bo, out, out, out);
}